// Round 1
// baseline (4518.657 us; speedup 1.0000x reference)
//
#include <hip/hip_runtime.h>
#include <cmath>

// Problem constants (fixed by the reference)
#define N_NODES 4096
#define FDIM    256
#define CDIM    40
#define NEDGE   131072
#define TWO_PI_F 6.28318530717958647692f

static constexpr size_t NN = (size_t)N_NODES * N_NODES;   // 16,777,216
static constexpr size_t NF = (size_t)N_NODES * FDIM;      // 1,048,576

// ---------------------------------------------------------------------------
// 1. Scatter edges into dense A (A must be pre-zeroed)
// ---------------------------------------------------------------------------
__global__ void scatter_edges(const int* __restrict__ edges,
                              const float* __restrict__ w,
                              float* __restrict__ A) {
    int e = blockIdx.x * blockDim.x + threadIdx.x;
    if (e < NEDGE) {
        int r = edges[e];
        int c = edges[NEDGE + e];
        atomicAdd(A + (size_t)r * N_NODES + c, w[e]);
    }
}

// ---------------------------------------------------------------------------
// 2a. Column sums of A (coalesced; partial sums per row-chunk, atomic combine;
//     colsum must be pre-zeroed)
// ---------------------------------------------------------------------------
__global__ __launch_bounds__(256) void colsum_k(const float* __restrict__ A,
                                                float* __restrict__ colsum) {
    int j  = blockIdx.x * 256 + threadIdx.x;   // column
    int i0 = blockIdx.y * 256;                 // row chunk
    float s = 0.f;
    for (int i = i0; i < i0 + 256; ++i) s += A[(size_t)i * N_NODES + j];
    atomicAdd(colsum + j, s);
}

// 2b. Row sums: one block per row, LDS reduce
__global__ __launch_bounds__(256) void rowsum_k(const float* __restrict__ A,
                                                float* __restrict__ rowsum) {
    int i = blockIdx.x;
    float s = 0.f;
    for (int j = threadIdx.x; j < N_NODES; j += 256)
        s += A[(size_t)i * N_NODES + j];
    __shared__ float red[256];
    red[threadIdx.x] = s;
    __syncthreads();
    for (int off = 128; off; off >>= 1) {
        if (threadIdx.x < off) red[threadIdx.x] += red[threadIdx.x + off];
        __syncthreads();
    }
    if (threadIdx.x == 0) rowsum[i] = red[0];
}

// 2c. dinv = (0.5*(rowsum+colsum))^-0.5 with 0 -> 1
__global__ void dinv_k(const float* __restrict__ rowsum,
                       const float* __restrict__ colsum,
                       float* __restrict__ dinv) {
    int j = blockIdx.x * blockDim.x + threadIdx.x;
    if (j < N_NODES) {
        float d = 0.5f * (rowsum[j] + colsum[j]);
        if (d == 0.f) d = 1.f;
        dinv[j] = 1.0f / sqrtf(d);
    }
}

// ---------------------------------------------------------------------------
// 3. Build conj(L) = -A_n * exp(-i*Theta). Processes (i,j)/(j,i) pairs so that
//    Lr can alias A (in-place overwrite is safe: each pair read+written by one
//    thread only).
// ---------------------------------------------------------------------------
__global__ __launch_bounds__(256) void build_L(float* __restrict__ A_Lr,
                                               float* __restrict__ Li,
                                               const float* __restrict__ dinv,
                                               const float* __restrict__ qptr) {
    int j = blockIdx.x * 16 + threadIdx.x;
    int i = blockIdx.y * 16 + threadIdx.y;
    if (j < i) return;
    size_t ij = (size_t)i * N_NODES + j;
    size_t ji = (size_t)j * N_NODES + i;
    float a = A_Lr[ij];
    float b = A_Lr[ji];
    float an = 0.5f * (a + b) * dinv[i] * dinv[j];
    float theta = TWO_PI_F * qptr[0] * (a - b);
    float s, c;
    sincosf(theta, &s, &c);
    float lr = -an * c;
    float li = an * s;         // conj: -A_n*(cos - i sin) = -an*cos + i*an*sin
    A_Lr[ij] = lr;  Li[ij] = li;
    A_Lr[ji] = lr;  Li[ji] = -li;   // theta_ji = -theta_ij
}

// ---------------------------------------------------------------------------
// 4. Complex SpMM (dense): O = alpha * (Lc @ X) + beta * C0
//    Lc = Lr + i*Li [N,N], X = Xr + i*Xi [N,F].
//    Tiled 64x64x16, 256 threads, 4x4 per thread, both real & imag outputs.
// ---------------------------------------------------------------------------
#define BM 64
#define BN 64
#define BK 16

__global__ __launch_bounds__(256) void cspmm(
    const float* __restrict__ Lr, const float* __restrict__ Li,
    const float* __restrict__ Xr, const float* __restrict__ Xi,
    const float* __restrict__ C0r, const float* __restrict__ C0i,
    float* __restrict__ Or, float* __restrict__ Oi,
    float alpha, float beta)
{
    __shared__ float sLr[BM][BK + 1];
    __shared__ float sLi[BM][BK + 1];
    __shared__ float sXr[BK][BN + 1];
    __shared__ float sXi[BK][BN + 1];

    int tx = threadIdx.x;              // 0..15
    int ty = threadIdx.y;              // 0..15
    int tid = ty * 16 + tx;
    int rowBase = blockIdx.y * BM;
    int colBase = blockIdx.x * BN;

    float accR[4][4] = {};
    float accI[4][4] = {};

    // load indices
    int lr_r  = tid >> 2;            // 0..63
    int lr_kc = (tid & 3) * 4;       // 0,4,8,12
    int lx_r  = tid >> 4;            // 0..15
    int lx_c  = (tid & 15) * 4;      // 0..60

    for (int kb = 0; kb < N_NODES; kb += BK) {
        {
            const float4 l4 = *(const float4*)(Lr + (size_t)(rowBase + lr_r) * N_NODES + kb + lr_kc);
            const float4 i4 = *(const float4*)(Li + (size_t)(rowBase + lr_r) * N_NODES + kb + lr_kc);
            sLr[lr_r][lr_kc + 0] = l4.x; sLr[lr_r][lr_kc + 1] = l4.y;
            sLr[lr_r][lr_kc + 2] = l4.z; sLr[lr_r][lr_kc + 3] = l4.w;
            sLi[lr_r][lr_kc + 0] = i4.x; sLi[lr_r][lr_kc + 1] = i4.y;
            sLi[lr_r][lr_kc + 2] = i4.z; sLi[lr_r][lr_kc + 3] = i4.w;
        }
        {
            const float4 r4 = *(const float4*)(Xr + (size_t)(kb + lx_r) * FDIM + colBase + lx_c);
            const float4 i4 = *(const float4*)(Xi + (size_t)(kb + lx_r) * FDIM + colBase + lx_c);
            sXr[lx_r][lx_c + 0] = r4.x; sXr[lx_r][lx_c + 1] = r4.y;
            sXr[lx_r][lx_c + 2] = r4.z; sXr[lx_r][lx_c + 3] = r4.w;
            sXi[lx_r][lx_c + 0] = i4.x; sXi[lx_r][lx_c + 1] = i4.y;
            sXi[lx_r][lx_c + 2] = i4.z; sXi[lx_r][lx_c + 3] = i4.w;
        }
        __syncthreads();

        #pragma unroll
        for (int kk = 0; kk < BK; ++kk) {
            float ar[4], ai[4], br[4], bi[4];
            #pragma unroll
            for (int m = 0; m < 4; ++m) {
                ar[m] = sLr[ty * 4 + m][kk];
                ai[m] = sLi[ty * 4 + m][kk];
            }
            #pragma unroll
            for (int n = 0; n < 4; ++n) {
                br[n] = sXr[kk][tx * 4 + n];
                bi[n] = sXi[kk][tx * 4 + n];
            }
            #pragma unroll
            for (int m = 0; m < 4; ++m)
                #pragma unroll
                for (int n = 0; n < 4; ++n) {
                    accR[m][n] += ar[m] * br[n];
                    accR[m][n] -= ai[m] * bi[n];
                    accI[m][n] += ar[m] * bi[n];
                    accI[m][n] += ai[m] * br[n];
                }
        }
        __syncthreads();
    }

    #pragma unroll
    for (int m = 0; m < 4; ++m)
        #pragma unroll
        for (int n = 0; n < 4; ++n) {
            int row = rowBase + ty * 4 + m;
            int col = colBase + tx * 4 + n;
            size_t idx = (size_t)row * FDIM + col;
            float vr = alpha * accR[m][n];
            float vi = alpha * accI[m][n];
            if (beta != 0.f) {
                vr += beta * C0r[idx];
                vi += beta * C0i[idx];
            }
            Or[idx] = vr;
            Oi[idx] = vi;
        }
}

// ---------------------------------------------------------------------------
// 5. W-apply: S = sum_k Z_k @ W[k] (complex Z, real W), then
//    out_r = bias - S_i ; out_i = bias + S_r       (Yc = i*S)
// ---------------------------------------------------------------------------
__global__ __launch_bounds__(256) void wapply(
    const float* __restrict__ Z0r, const float* __restrict__ Z0i,
    const float* __restrict__ Z1r, const float* __restrict__ Z1i,
    const float* __restrict__ Z2r, const float* __restrict__ Z2i,
    const float* __restrict__ W,      // [3][256][256]
    const float* __restrict__ bias,   // [256]
    float* __restrict__ Or, float* __restrict__ Oi)
{
    __shared__ float sZr[BM][BK + 1];
    __shared__ float sZi[BM][BK + 1];
    __shared__ float sW[BK][BN + 1];

    int tx = threadIdx.x, ty = threadIdx.y;
    int tid = ty * 16 + tx;
    int rowBase = blockIdx.y * BM;
    int colBase = blockIdx.x * BN;

    float accSr[4][4] = {};
    float accSi[4][4] = {};

    int lz_r  = tid >> 2;
    int lz_kc = (tid & 3) * 4;
    int lw_r  = tid >> 4;
    int lw_c  = (tid & 15) * 4;

    for (int kb = 0; kb < 3 * FDIM; kb += BK) {
        int order = kb >> 8;
        int kloc  = kb & 255;
        const float* Zr = (order == 0) ? Z0r : (order == 1) ? Z1r : Z2r;
        const float* Zi = (order == 0) ? Z0i : (order == 1) ? Z1i : Z2i;

        {
            const float4 r4 = *(const float4*)(Zr + (size_t)(rowBase + lz_r) * FDIM + kloc + lz_kc);
            const float4 i4 = *(const float4*)(Zi + (size_t)(rowBase + lz_r) * FDIM + kloc + lz_kc);
            sZr[lz_r][lz_kc + 0] = r4.x; sZr[lz_r][lz_kc + 1] = r4.y;
            sZr[lz_r][lz_kc + 2] = r4.z; sZr[lz_r][lz_kc + 3] = r4.w;
            sZi[lz_r][lz_kc + 0] = i4.x; sZi[lz_r][lz_kc + 1] = i4.y;
            sZi[lz_r][lz_kc + 2] = i4.z; sZi[lz_r][lz_kc + 3] = i4.w;
        }
        {
            const float4 w4 = *(const float4*)(W + (size_t)order * FDIM * FDIM
                                               + (size_t)(kloc + lw_r) * FDIM + colBase + lw_c);
            sW[lw_r][lw_c + 0] = w4.x; sW[lw_r][lw_c + 1] = w4.y;
            sW[lw_r][lw_c + 2] = w4.z; sW[lw_r][lw_c + 3] = w4.w;
        }
        __syncthreads();

        #pragma unroll
        for (int kk = 0; kk < BK; ++kk) {
            float zr[4], zi[4], w[4];
            #pragma unroll
            for (int m = 0; m < 4; ++m) {
                zr[m] = sZr[ty * 4 + m][kk];
                zi[m] = sZi[ty * 4 + m][kk];
            }
            #pragma unroll
            for (int n = 0; n < 4; ++n) w[n] = sW[kk][tx * 4 + n];
            #pragma unroll
            for (int m = 0; m < 4; ++m)
                #pragma unroll
                for (int n = 0; n < 4; ++n) {
                    accSr[m][n] += zr[m] * w[n];
                    accSi[m][n] += zi[m] * w[n];
                }
        }
        __syncthreads();
    }

    #pragma unroll
    for (int m = 0; m < 4; ++m)
        #pragma unroll
        for (int n = 0; n < 4; ++n) {
            int row = rowBase + ty * 4 + m;
            int col = colBase + tx * 4 + n;
            size_t idx = (size_t)row * FDIM + col;
            float bv = bias[col];
            Or[idx] = bv - accSi[m][n];
            Oi[idx] = bv + accSr[m][n];
        }
}

// ---------------------------------------------------------------------------
// 6. Head: logits = [r,i] @ Wc^T + bc; out = log_softmax(logits)
//    One 64-thread wave per row.
// ---------------------------------------------------------------------------
__global__ __launch_bounds__(64) void head_k(
    const float* __restrict__ Yr, const float* __restrict__ Yi,
    const float* __restrict__ Wc,   // [40][512]
    const float* __restrict__ bc,   // [40]
    float* __restrict__ out)        // [N][40]
{
    int n = blockIdx.x;
    int t = threadIdx.x;
    __shared__ float x[2 * FDIM];
    for (int k = t; k < FDIM; k += 64) {
        x[k]        = Yr[(size_t)n * FDIM + k];
        x[FDIM + k] = Yi[(size_t)n * FDIM + k];
    }
    __syncthreads();

    float logit = -INFINITY;
    if (t < CDIM) {
        float s = bc[t];
        const float* w = Wc + (size_t)t * (2 * FDIM);
        #pragma unroll 8
        for (int k = 0; k < 2 * FDIM; ++k) s += x[k] * w[k];
        logit = s;
    }
    // wave-64 reductions
    float m = logit;
    for (int off = 32; off; off >>= 1) m = fmaxf(m, __shfl_down(m, off));
    m = __shfl(m, 0);
    float e = (t < CDIM) ? expf(logit - m) : 0.f;
    float se = e;
    for (int off = 32; off; off >>= 1) se += __shfl_down(se, off);
    se = __shfl(se, 0);
    float lse = m + logf(se);
    if (t < CDIM) out[(size_t)n * CDIM + t] = logit - lse;
}

// ---------------------------------------------------------------------------
// Launcher
// ---------------------------------------------------------------------------
extern "C" void kernel_launch(void* const* d_in, const int* in_sizes, int n_in,
                              void* d_out, int out_size, void* d_ws, size_t ws_size,
                              hipStream_t stream) {
    const float* real = (const float*)d_in[0];
    const float* imag = (const float*)d_in[1];
    const int*   edges = (const int*)d_in[2];
    const float* q    = (const float*)d_in[3];
    const float* ew   = (const float*)d_in[4];
    const float* W1   = (const float*)d_in[5];
    const float* b1   = (const float*)d_in[6];
    const float* W2   = (const float*)d_in[7];
    const float* b2   = (const float*)d_in[8];
    const float* Wc   = (const float*)d_in[9];
    const float* bc   = (const float*)d_in[10];
    float* out = (float*)d_out;

    float* ws = (float*)d_ws;
    // Workspace layout (floats)
    float* A_Lr   = ws;                    // NN  (A, overwritten in-place by Lr)
    float* colsum = ws + NN;               // N
    float* rowsum = colsum + N_NODES;      // N
    float* dinv   = rowsum + N_NODES;      // N
    float* Li     = ws + NN + 16384;       // NN
    float* Z1r = Li + NN;                  // 8 x NF
    float* Z1i = Z1r + NF;
    float* Z2r = Z1i + NF;
    float* Z2i = Z2r + NF;
    float* Y1r = Z2i + NF;
    float* Y1i = Y1r + NF;
    float* Y2r = Y1i + NF;
    float* Y2i = Y2r + NF;

    // zero A + colsum (both accumulated into)
    hipMemsetAsync(d_ws, 0, (NN + N_NODES) * sizeof(float), stream);

    scatter_edges<<<(NEDGE + 255) / 256, 256, 0, stream>>>(edges, ew, A_Lr);
    colsum_k<<<dim3(16, 16), 256, 0, stream>>>(A_Lr, colsum);
    rowsum_k<<<N_NODES, 256, 0, stream>>>(A_Lr, rowsum);
    dinv_k<<<16, 256, 0, stream>>>(rowsum, colsum, dinv);
    build_L<<<dim3(256, 256), dim3(16, 16), 0, stream>>>(A_Lr, Li, dinv, q);

    const float* Lr = A_Lr;
    dim3 gG(FDIM / BN, N_NODES / BM);   // (4, 64)
    dim3 bG(16, 16);

    // Layer 1
    cspmm<<<gG, bG, 0, stream>>>(Lr, Li, real, imag, nullptr, nullptr,
                                 Z1r, Z1i, 1.f, 0.f);
    cspmm<<<gG, bG, 0, stream>>>(Lr, Li, Z1r, Z1i, real, imag,
                                 Z2r, Z2i, 2.f, -1.f);
    wapply<<<gG, bG, 0, stream>>>(real, imag, Z1r, Z1i, Z2r, Z2i, W1, b1, Y1r, Y1i);

    // Layer 2
    cspmm<<<gG, bG, 0, stream>>>(Lr, Li, Y1r, Y1i, nullptr, nullptr,
                                 Z1r, Z1i, 1.f, 0.f);
    cspmm<<<gG, bG, 0, stream>>>(Lr, Li, Z1r, Z1i, Y1r, Y1i,
                                 Z2r, Z2i, 2.f, -1.f);
    wapply<<<gG, bG, 0, stream>>>(Y1r, Y1i, Z1r, Z1i, Z2r, Z2i, W2, b2, Y2r, Y2i);

    // Head
    head_k<<<N_NODES, 64, 0, stream>>>(Y2r, Y2i, Wc, bc, out);
}

// Round 2
// 622.524 us; speedup vs baseline: 7.2586x; 7.2586x over previous
//
#include <hip/hip_runtime.h>
#include <cmath>

#define N_NODES 4096
#define FDIM    256
#define CDIM    40
#define NEDGE   131072
#define TWO_PI_F 6.28318530717958647692f

typedef __bf16 bf16;
typedef __bf16 bf16x8 __attribute__((ext_vector_type(8)));
typedef float  f32x4  __attribute__((ext_vector_type(4)));

static constexpr size_t NN = (size_t)N_NODES * N_NODES;   // 16,777,216
static constexpr size_t NF = (size_t)N_NODES * FDIM;      // 1,048,576

// async global->LDS, 16B per lane, dest = ldsBase + lane*16
__device__ __forceinline__ void gld_lds16(const bf16* g, bf16* s) {
    __builtin_amdgcn_global_load_lds(
        (const __attribute__((address_space(1))) void*)g,
        (__attribute__((address_space(3))) void*)s,
        16, 0, 0);
}

// ---------------------------------------------------------------------------
// 1. Scatter edges into dense A (A pre-zeroed)
// ---------------------------------------------------------------------------
__global__ void scatter_edges(const int* __restrict__ edges,
                              const float* __restrict__ w,
                              float* __restrict__ A) {
    int e = blockIdx.x * blockDim.x + threadIdx.x;
    if (e < NEDGE) {
        int r = edges[e];
        int c = edges[NEDGE + e];
        atomicAdd(A + (size_t)r * N_NODES + c, w[e]);
    }
}

// 2a. Column sums (colsum pre-zeroed)
__global__ __launch_bounds__(256) void colsum_k(const float* __restrict__ A,
                                                float* __restrict__ colsum) {
    int j  = blockIdx.x * 256 + threadIdx.x;
    int i0 = blockIdx.y * 256;
    float s = 0.f;
    for (int i = i0; i < i0 + 256; ++i) s += A[(size_t)i * N_NODES + j];
    atomicAdd(colsum + j, s);
}

// 2b. Row sums
__global__ __launch_bounds__(256) void rowsum_k(const float* __restrict__ A,
                                                float* __restrict__ rowsum) {
    int i = blockIdx.x;
    float s = 0.f;
    for (int j = threadIdx.x; j < N_NODES; j += 256)
        s += A[(size_t)i * N_NODES + j];
    __shared__ float red[256];
    red[threadIdx.x] = s;
    __syncthreads();
    for (int off = 128; off; off >>= 1) {
        if (threadIdx.x < off) red[threadIdx.x] += red[threadIdx.x + off];
        __syncthreads();
    }
    if (threadIdx.x == 0) rowsum[i] = red[0];
}

// 2c. dinv
__global__ void dinv_k(const float* __restrict__ rowsum,
                       const float* __restrict__ colsum,
                       float* __restrict__ dinv) {
    int j = blockIdx.x * blockDim.x + threadIdx.x;
    if (j < N_NODES) {
        float d = 0.5f * (rowsum[j] + colsum[j]);
        if (d == 0.f) d = 1.f;
        dinv[j] = 1.0f / sqrtf(d);
    }
}

// ---------------------------------------------------------------------------
// 3. build conj(L) = -A_n * exp(-i*Theta), write bf16 directly
// ---------------------------------------------------------------------------
__global__ __launch_bounds__(256) void build_L(const float* __restrict__ A,
                                               bf16* __restrict__ Lr16,
                                               bf16* __restrict__ Li16,
                                               const float* __restrict__ dinv,
                                               const float* __restrict__ qptr) {
    int j = blockIdx.x * 16 + threadIdx.x;
    int i = blockIdx.y * 16 + threadIdx.y;
    if (j < i) return;
    size_t ij = (size_t)i * N_NODES + j;
    size_t ji = (size_t)j * N_NODES + i;
    float a = A[ij];
    float b = A[ji];
    float an = 0.5f * (a + b) * dinv[i] * dinv[j];
    float theta = TWO_PI_F * qptr[0] * (a - b);
    float s, c;
    sincosf(theta, &s, &c);
    float lr = -an * c;
    float li = an * s;            // conj(L) = -an*cos + i*an*sin
    Lr16[ij] = (bf16)lr;  Li16[ij] = (bf16)li;
    Lr16[ji] = (bf16)lr;  Li16[ji] = (bf16)(-li);
}

// ---------------------------------------------------------------------------
// 4. cast input X -> bf16 row-major [4096][256] and transposed [256][4096]
// ---------------------------------------------------------------------------
__global__ __launch_bounds__(256) void cast_in(const float* __restrict__ Xr,
                                               const float* __restrict__ Xi,
                                               bf16* __restrict__ Xr16, bf16* __restrict__ Xi16,
                                               bf16* __restrict__ Xr16t, bf16* __restrict__ Xi16t) {
    int idx = blockIdx.x * 256 + threadIdx.x;      // 0 .. NF-1
    int n = idx >> 8, f = idx & 255;
    float vr = Xr[idx], vi = Xi[idx];
    Xr16[idx] = (bf16)vr;  Xi16[idx] = (bf16)vi;
    Xr16t[(size_t)f * N_NODES + n] = (bf16)vr;
    Xi16t[(size_t)f * N_NODES + n] = (bf16)vi;
}

// cast W [3][256][256] -> Wt bf16 [256][768], Wt[n][o*256+k] = W[o][k][n]
__global__ __launch_bounds__(256) void cast_w(const float* __restrict__ W,
                                              bf16* __restrict__ Wt) {
    int idx = blockIdx.x * 256 + threadIdx.x;      // 0 .. 256*768-1
    if (idx < 256 * 768) {
        int nout = idx / 768, kk = idx - nout * 768;
        int o = kk >> 8, k = kk & 255;
        Wt[idx] = (bf16)W[((size_t)o * 256 + k) * 256 + nout];
    }
}

// ---------------------------------------------------------------------------
// 5. Complex GEMM via bf16 MFMA:  O = alpha*(Lc @ Xc) + beta*C0
//    A = Lr/Li [4096][4096] bf16 (k contiguous), B = Xrt/Xit [256][4096] bf16
//    BM=BN=64, BK=32, 256 threads (4 waves, 32x32 quadrant each).
//    Epilogue optionally writes fp32, bf16 row-major, bf16 transposed.
// ---------------------------------------------------------------------------
__global__ __launch_bounds__(256) void cspmm_mfma(
    const bf16* __restrict__ Lr, const bf16* __restrict__ Li,
    const bf16* __restrict__ Brt, const bf16* __restrict__ Bit,
    const float* __restrict__ C0r, const float* __restrict__ C0i,
    float* __restrict__ O32r, float* __restrict__ O32i,
    bf16* __restrict__ O16r_r, bf16* __restrict__ O16r_i,
    bf16* __restrict__ O16t_r, bf16* __restrict__ O16t_i,
    float alpha, float beta)
{
    __shared__ __align__(16) bf16 sLr[64 * 32];
    __shared__ __align__(16) bf16 sLi[64 * 32];
    __shared__ __align__(16) bf16 sBr[64 * 32];
    __shared__ __align__(16) bf16 sBi[64 * 32];

    const int tid  = threadIdx.x;
    const int wave = tid >> 6;
    const int lane = tid & 63;
    const int rowBase = blockIdx.y * 64;
    const int colBase = blockIdx.x * 64;

    // staging: each wave owns one matrix; 4x 16B-per-lane instrs cover 64 rows x 32 k
    const bf16* gmat = (wave == 0) ? Lr : (wave == 1) ? Li : (wave == 2) ? Brt : Bit;
    bf16* smat = (wave == 0) ? sLr : (wave == 1) ? sLi : (wave == 2) ? sBr : sBi;
    const int gbase = (wave < 2) ? rowBase : colBase;
    const int srow = lane >> 2;            // 4 lanes per 64B row
    const int skc  = (lane & 3) * 8;       // element offset within row
    const size_t goff = (size_t)(gbase + srow) * N_NODES + skc;

    f32x4 accRR[2][2] = {{{0.f}}}, accII[2][2] = {{{0.f}}}, accOI[2][2] = {{{0.f}}};
    const int wm = wave & 1, wn = wave >> 1;
    const int fr = lane & 15;
    const int fk = (lane >> 4) * 8;

    for (int kb = 0; kb < N_NODES; kb += 32) {
        const bf16* g = gmat + goff + kb;
        #pragma unroll
        for (int t = 0; t < 4; ++t)
            gld_lds16(g + (size_t)t * 16 * N_NODES, smat + t * 512);
        __syncthreads();

        bf16x8 aR[2], aI[2], bR[2], bI[2];
        #pragma unroll
        for (int m = 0; m < 2; ++m) {
            int r = wm * 32 + m * 16 + fr;
            aR[m] = *(const bf16x8*)&sLr[r * 32 + fk];
            aI[m] = *(const bf16x8*)&sLi[r * 32 + fk];
        }
        #pragma unroll
        for (int n = 0; n < 2; ++n) {
            int c = wn * 32 + n * 16 + fr;
            bR[n] = *(const bf16x8*)&sBr[c * 32 + fk];
            bI[n] = *(const bf16x8*)&sBi[c * 32 + fk];
        }
        #pragma unroll
        for (int m = 0; m < 2; ++m)
            #pragma unroll
            for (int n = 0; n < 2; ++n) {
                accRR[m][n] = __builtin_amdgcn_mfma_f32_16x16x32_bf16(aR[m], bR[n], accRR[m][n], 0, 0, 0);
                accII[m][n] = __builtin_amdgcn_mfma_f32_16x16x32_bf16(aI[m], bI[n], accII[m][n], 0, 0, 0);
                accOI[m][n] = __builtin_amdgcn_mfma_f32_16x16x32_bf16(aR[m], bI[n], accOI[m][n], 0, 0, 0);
                accOI[m][n] = __builtin_amdgcn_mfma_f32_16x16x32_bf16(aI[m], bR[n], accOI[m][n], 0, 0, 0);
            }
        __syncthreads();
    }

    // epilogue: C/D layout col=lane&15, row=(lane>>4)*4+reg
    #pragma unroll
    for (int m = 0; m < 2; ++m)
        #pragma unroll
        for (int n = 0; n < 2; ++n) {
            int row0 = rowBase + wm * 32 + m * 16 + (lane >> 4) * 4;
            int col  = colBase + wn * 32 + n * 16 + (lane & 15);
            #pragma unroll
            for (int r = 0; r < 4; ++r) {
                float vr = alpha * (accRR[m][n][r] - accII[m][n][r]);
                float vi = alpha * accOI[m][n][r];
                size_t idx = (size_t)(row0 + r) * FDIM + col;
                if (C0r)  { vr += beta * C0r[idx]; vi += beta * C0i[idx]; }
                if (O32r) { O32r[idx] = vr; O32i[idx] = vi; }
                if (O16r_r) { O16r_r[idx] = (bf16)vr; O16r_i[idx] = (bf16)vi; }
                if (O16t_r) {
                    size_t tidx = (size_t)col * N_NODES + row0 + r;
                    O16t_r[tidx] = (bf16)vr; O16t_i[tidx] = (bf16)vi;
                }
            }
        }
}

// ---------------------------------------------------------------------------
// 6. wapply via MFMA: S = [Z0|Z1|Z2] @ Wcat (K=768), then
//    Or = bias - Si ; Oi = bias + Sr
// ---------------------------------------------------------------------------
__global__ __launch_bounds__(256) void wapply_mfma(
    const bf16* __restrict__ Z0r, const bf16* __restrict__ Z0i,
    const bf16* __restrict__ Z1r, const bf16* __restrict__ Z1i,
    const bf16* __restrict__ Z2r, const bf16* __restrict__ Z2i,
    const bf16* __restrict__ Wt,      // [256][768]
    const float* __restrict__ bias,   // [256]
    float* __restrict__ O32r, float* __restrict__ O32i,
    bf16* __restrict__ O16r_r, bf16* __restrict__ O16r_i,
    bf16* __restrict__ O16t_r, bf16* __restrict__ O16t_i)
{
    __shared__ __align__(16) bf16 sZr[64 * 32];
    __shared__ __align__(16) bf16 sZi[64 * 32];
    __shared__ __align__(16) bf16 sW [64 * 32];

    const int tid  = threadIdx.x;
    const int wave = tid >> 6;
    const int lane = tid & 63;
    const int rowBase = blockIdx.y * 64;
    const int colBase = blockIdx.x * 64;

    const int srow = lane >> 2;
    const int skc  = (lane & 3) * 8;

    f32x4 accSr[2][2] = {{{0.f}}}, accSi[2][2] = {{{0.f}}};
    const int wm = wave & 1, wn = wave >> 1;
    const int fr = lane & 15;
    const int fk = (lane >> 4) * 8;

    for (int kb = 0; kb < 3 * FDIM; kb += 32) {
        int order = kb >> 8;
        int kloc  = kb & 255;
        if (wave == 0 || wave == 1) {
            const bf16* z;
            if (wave == 0) z = (order == 0) ? Z0r : (order == 1) ? Z1r : Z2r;
            else           z = (order == 0) ? Z0i : (order == 1) ? Z1i : Z2i;
            bf16* s = (wave == 0) ? sZr : sZi;
            const bf16* g = z + (size_t)(rowBase + srow) * FDIM + kloc + skc;
            #pragma unroll
            for (int t = 0; t < 4; ++t)
                gld_lds16(g + (size_t)t * 16 * FDIM, s + t * 512);
        } else if (wave == 2) {
            const bf16* g = Wt + (size_t)(colBase + srow) * 768 + kb + skc;
            #pragma unroll
            for (int t = 0; t < 4; ++t)
                gld_lds16(g + (size_t)t * 16 * 768, sW + t * 512);
        }
        __syncthreads();

        bf16x8 zr[2], zi[2], wv[2];
        #pragma unroll
        for (int m = 0; m < 2; ++m) {
            int r = wm * 32 + m * 16 + fr;
            zr[m] = *(const bf16x8*)&sZr[r * 32 + fk];
            zi[m] = *(const bf16x8*)&sZi[r * 32 + fk];
        }
        #pragma unroll
        for (int n = 0; n < 2; ++n) {
            int c = wn * 32 + n * 16 + fr;
            wv[n] = *(const bf16x8*)&sW[c * 32 + fk];
        }
        #pragma unroll
        for (int m = 0; m < 2; ++m)
            #pragma unroll
            for (int n = 0; n < 2; ++n) {
                accSr[m][n] = __builtin_amdgcn_mfma_f32_16x16x32_bf16(zr[m], wv[n], accSr[m][n], 0, 0, 0);
                accSi[m][n] = __builtin_amdgcn_mfma_f32_16x16x32_bf16(zi[m], wv[n], accSi[m][n], 0, 0, 0);
            }
        __syncthreads();
    }

    #pragma unroll
    for (int m = 0; m < 2; ++m)
        #pragma unroll
        for (int n = 0; n < 2; ++n) {
            int row0 = rowBase + wm * 32 + m * 16 + (lane >> 4) * 4;
            int col  = colBase + wn * 32 + n * 16 + (lane & 15);
            float bv = bias[col];
            #pragma unroll
            for (int r = 0; r < 4; ++r) {
                float vr = bv - accSi[m][n][r];
                float vi = bv + accSr[m][n][r];
                size_t idx = (size_t)(row0 + r) * FDIM + col;
                if (O32r)   { O32r[idx] = vr; O32i[idx] = vi; }
                if (O16r_r) { O16r_r[idx] = (bf16)vr; O16r_i[idx] = (bf16)vi; }
                if (O16t_r) {
                    size_t tidx = (size_t)col * N_NODES + row0 + r;
                    O16t_r[tidx] = (bf16)vr; O16t_i[tidx] = (bf16)vi;
                }
            }
        }
}

// ---------------------------------------------------------------------------
// 7. Head: logits = [r,i] @ Wc^T + bc; out = log_softmax
// ---------------------------------------------------------------------------
__global__ __launch_bounds__(64) void head_k(
    const float* __restrict__ Yr, const float* __restrict__ Yi,
    const float* __restrict__ Wc,   // [40][512]
    const float* __restrict__ bc,   // [40]
    float* __restrict__ out)        // [N][40]
{
    int n = blockIdx.x;
    int t = threadIdx.x;
    __shared__ float x[2 * FDIM];
    for (int k = t; k < FDIM; k += 64) {
        x[k]        = Yr[(size_t)n * FDIM + k];
        x[FDIM + k] = Yi[(size_t)n * FDIM + k];
    }
    __syncthreads();

    float logit = -INFINITY;
    if (t < CDIM) {
        float s = bc[t];
        const float* w = Wc + (size_t)t * (2 * FDIM);
        #pragma unroll 8
        for (int k = 0; k < 2 * FDIM; ++k) s += x[k] * w[k];
        logit = s;
    }
    float m = logit;
    for (int off = 32; off; off >>= 1) m = fmaxf(m, __shfl_down(m, off));
    m = __shfl(m, 0);
    float e = (t < CDIM) ? expf(logit - m) : 0.f;
    float se = e;
    for (int off = 32; off; off >>= 1) se += __shfl_down(se, off);
    se = __shfl(se, 0);
    float lse = m + logf(se);
    if (t < CDIM) out[(size_t)n * CDIM + t] = logit - lse;
}

// ---------------------------------------------------------------------------
// Launcher
// ---------------------------------------------------------------------------
extern "C" void kernel_launch(void* const* d_in, const int* in_sizes, int n_in,
                              void* d_out, int out_size, void* d_ws, size_t ws_size,
                              hipStream_t stream) {
    const float* real = (const float*)d_in[0];
    const float* imag = (const float*)d_in[1];
    const int*   edges = (const int*)d_in[2];
    const float* q    = (const float*)d_in[3];
    const float* ew   = (const float*)d_in[4];
    const float* W1   = (const float*)d_in[5];
    const float* b1   = (const float*)d_in[6];
    const float* W2   = (const float*)d_in[7];
    const float* b2   = (const float*)d_in[8];
    const float* Wc   = (const float*)d_in[9];
    const float* bc   = (const float*)d_in[10];
    float* out = (float*)d_out;

    // ---- workspace carve-up (all chunks 16B-aligned) ----
    char* w = (char*)d_ws;
    float* A      = (float*)w;  w += NN * 4;                 // 64 MB
    float* colsum = (float*)w;  w += N_NODES * 4;
    float* rowsum = (float*)w;  w += N_NODES * 4;
    float* dinv   = (float*)w;  w += N_NODES * 4;
    w += 4096;  // pad to keep 16B alignment headroom
    bf16* Lr16 = (bf16*)w;  w += NN * 2;                     // 32 MB
    bf16* Li16 = (bf16*)w;  w += NN * 2;                     // 32 MB
    bf16* Xr16  = (bf16*)w; w += NF * 2;                     // 2 MB each
    bf16* Xi16  = (bf16*)w; w += NF * 2;
    bf16* Xr16t = (bf16*)w; w += NF * 2;
    bf16* Xi16t = (bf16*)w; w += NF * 2;
    bf16* Z1r16  = (bf16*)w; w += NF * 2;
    bf16* Z1i16  = (bf16*)w; w += NF * 2;
    bf16* Z1r16t = (bf16*)w; w += NF * 2;
    bf16* Z1i16t = (bf16*)w; w += NF * 2;
    bf16* Z2r16  = (bf16*)w; w += NF * 2;
    bf16* Z2i16  = (bf16*)w; w += NF * 2;
    float* Y1r = (float*)w; w += NF * 4;                     // 4 MB each
    float* Y1i = (float*)w; w += NF * 4;
    bf16* Y1r16  = (bf16*)w; w += NF * 2;
    bf16* Y1i16  = (bf16*)w; w += NF * 2;
    bf16* Y1r16t = (bf16*)w; w += NF * 2;
    bf16* Y1i16t = (bf16*)w; w += NF * 2;
    float* Y2r = (float*)w; w += NF * 4;
    float* Y2i = (float*)w; w += NF * 4;
    bf16* W1t = (bf16*)w; w += 256 * 768 * 2;
    bf16* W2t = (bf16*)w; w += 256 * 768 * 2;

    // zero A + colsum (accumulated into)
    hipMemsetAsync(A, 0, (NN + N_NODES) * sizeof(float), stream);

    scatter_edges<<<(NEDGE + 255) / 256, 256, 0, stream>>>(edges, ew, A);
    colsum_k<<<dim3(16, 16), 256, 0, stream>>>(A, colsum);
    rowsum_k<<<N_NODES, 256, 0, stream>>>(A, rowsum);
    dinv_k<<<16, 256, 0, stream>>>(rowsum, colsum, dinv);
    build_L<<<dim3(256, 256), dim3(16, 16), 0, stream>>>(A, Lr16, Li16, dinv, q);

    cast_in<<<NF / 256, 256, 0, stream>>>(real, imag, Xr16, Xi16, Xr16t, Xi16t);
    cast_w<<<(256 * 768 + 255) / 256, 256, 0, stream>>>(W1, W1t);
    cast_w<<<(256 * 768 + 255) / 256, 256, 0, stream>>>(W2, W2t);

    dim3 gG(FDIM / 64, N_NODES / 64);   // (4, 64) = 256 blocks
    dim3 bG(256);

    // ---- Layer 1 ----
    // Z1 = L @ X          -> bf16 row + bf16 transposed
    cspmm_mfma<<<gG, bG, 0, stream>>>(Lr16, Li16, Xr16t, Xi16t,
                                      nullptr, nullptr,
                                      nullptr, nullptr,
                                      Z1r16, Z1i16, Z1r16t, Z1i16t,
                                      1.f, 0.f);
    // Z2 = 2 L @ Z1 - X   -> bf16 row only
    cspmm_mfma<<<gG, bG, 0, stream>>>(Lr16, Li16, Z1r16t, Z1i16t,
                                      real, imag,
                                      nullptr, nullptr,
                                      Z2r16, Z2i16, nullptr, nullptr,
                                      2.f, -1.f);
    // Y1 = i*(Z@W1) + b1  -> fp32 + bf16 row + bf16 transposed
    wapply_mfma<<<gG, bG, 0, stream>>>(Xr16, Xi16, Z1r16, Z1i16, Z2r16, Z2i16,
                                       W1t, b1,
                                       Y1r, Y1i, Y1r16, Y1i16, Y1r16t, Y1i16t);

    // ---- Layer 2 ----
    cspmm_mfma<<<gG, bG, 0, stream>>>(Lr16, Li16, Y1r16t, Y1i16t,
                                      nullptr, nullptr,
                                      nullptr, nullptr,
                                      Z1r16, Z1i16, Z1r16t, Z1i16t,
                                      1.f, 0.f);
    cspmm_mfma<<<gG, bG, 0, stream>>>(Lr16, Li16, Z1r16t, Z1i16t,
                                      Y1r, Y1i,
                                      nullptr, nullptr,
                                      Z2r16, Z2i16, nullptr, nullptr,
                                      2.f, -1.f);
    wapply_mfma<<<gG, bG, 0, stream>>>(Y1r16, Y1i16, Z1r16, Z1i16, Z2r16, Z2i16,
                                       W2t, b2,
                                       Y2r, Y2i, nullptr, nullptr, nullptr, nullptr);

    // ---- Head ----
    head_k<<<N_NODES, 64, 0, stream>>>(Y2r, Y2i, Wc, bc, out);
}

// Round 3
// 414.292 us; speedup vs baseline: 10.9069x; 1.5026x over previous
//
#include <hip/hip_runtime.h>
#include <cmath>

#define N_NODES 4096
#define FDIM    256
#define CDIM    40
#define NEDGE   131072
#define TWO_PI_F 6.28318530717958647692f

typedef __bf16 bf16;
typedef __bf16 bf16x8 __attribute__((ext_vector_type(8)));
typedef float  f32x4  __attribute__((ext_vector_type(4)));

static constexpr size_t NN = (size_t)N_NODES * N_NODES;   // 16,777,216
static constexpr size_t NF = (size_t)N_NODES * FDIM;      // 1,048,576

// async global->LDS, 16B per lane, dest = ldsBase + lane*16
__device__ __forceinline__ void gld_lds16(const bf16* g, bf16* s) {
    __builtin_amdgcn_global_load_lds(
        (const __attribute__((address_space(1))) void*)g,
        (__attribute__((address_space(3))) void*)s,
        16, 0, 0);
}

// ---------------------------------------------------------------------------
// 1. Scatter edges into dense A (A pre-zeroed)
// ---------------------------------------------------------------------------
__global__ void scatter_edges(const int* __restrict__ edges,
                              const float* __restrict__ w,
                              float* __restrict__ A) {
    int e = blockIdx.x * blockDim.x + threadIdx.x;
    if (e < NEDGE) {
        int r = edges[e];
        int c = edges[NEDGE + e];
        atomicAdd(A + (size_t)r * N_NODES + c, w[e]);
    }
}

// ---------------------------------------------------------------------------
// 2. Fused row+col sums, single pass over A. rowsum/colsum pre-zeroed.
//    grid (4, 64): block = 64 rows x 1024 cols.
// ---------------------------------------------------------------------------
__global__ __launch_bounds__(256) void degree_k(const float* __restrict__ A,
                                                float* __restrict__ rowsum,
                                                float* __restrict__ colsum) {
    int t  = threadIdx.x;
    int c0 = blockIdx.x * 1024;
    int r0 = blockIdx.y * 64;
    float colacc[4] = {0.f, 0.f, 0.f, 0.f};
    for (int r = 0; r < 64; ++r) {
        const float* row = A + (size_t)(r0 + r) * N_NODES + c0;
        float rs = 0.f;
        #pragma unroll
        for (int k = 0; k < 4; ++k) {
            float v = row[t + k * 256];
            rs += v;
            colacc[k] += v;
        }
        for (int off = 32; off; off >>= 1) rs += __shfl_down(rs, off);
        if ((t & 63) == 0) atomicAdd(rowsum + r0 + r, rs);
    }
    #pragma unroll
    for (int k = 0; k < 4; ++k)
        atomicAdd(colsum + c0 + t + k * 256, colacc[k]);
}

// 2c. dinv
__global__ void dinv_k(const float* __restrict__ rowsum,
                       const float* __restrict__ colsum,
                       float* __restrict__ dinv) {
    int j = blockIdx.x * blockDim.x + threadIdx.x;
    if (j < N_NODES) {
        float d = 0.5f * (rowsum[j] + colsum[j]);
        if (d == 0.f) d = 1.f;
        dinv[j] = 1.0f / sqrtf(d);
    }
}

// ---------------------------------------------------------------------------
// 3. build conj(L): tile-pair version, all accesses coalesced via LDS
//    transpose. grid (64, 64), upper triangle only (J >= I).
// ---------------------------------------------------------------------------
__global__ __launch_bounds__(256) void build_L_pair(const float* __restrict__ A,
                                                    bf16* __restrict__ Lr,
                                                    bf16* __restrict__ Li,
                                                    const float* __restrict__ dinv,
                                                    const float* __restrict__ qptr) {
    int J = blockIdx.x, I = blockIdx.y;
    if (J < I) return;
    int i0 = I * 64, j0 = J * 64;
    __shared__ float sA[64][65];
    __shared__ float sB[64][65];
    float w2pq = TWO_PI_F * qptr[0];
    int t = threadIdx.x;
    #pragma unroll 4
    for (int e = 0; e < 16; ++e) {
        int idx = t + e * 256; int r = idx >> 6, c = idx & 63;
        sA[r][c] = A[(size_t)(i0 + r) * N_NODES + j0 + c];
        sB[r][c] = A[(size_t)(j0 + r) * N_NODES + i0 + c];
    }
    __syncthreads();
    #pragma unroll 2
    for (int e = 0; e < 16; ++e) {
        int idx = t + e * 256; int r = idx >> 6, c = idx & 63;
        {   // tile (I,J): element (i0+r, j0+c)
            float a = sA[r][c], b = sB[c][r];
            float an = 0.5f * (a + b) * dinv[i0 + r] * dinv[j0 + c];
            float s, cs; sincosf(w2pq * (a - b), &s, &cs);
            size_t o = (size_t)(i0 + r) * N_NODES + j0 + c;
            Lr[o] = (bf16)(-an * cs); Li[o] = (bf16)(an * s);
        }
        {   // tile (J,I): element (j0+r, i0+c)
            float a = sB[r][c], b = sA[c][r];
            float an = 0.5f * (a + b) * dinv[j0 + r] * dinv[i0 + c];
            float s, cs; sincosf(w2pq * (a - b), &s, &cs);
            size_t o = (size_t)(j0 + r) * N_NODES + i0 + c;
            Lr[o] = (bf16)(-an * cs); Li[o] = (bf16)(an * s);
        }
    }
}

// ---------------------------------------------------------------------------
// 4. cast X -> bf16 row-major and transposed (LDS-tiled). grid (4, 64).
// ---------------------------------------------------------------------------
__global__ __launch_bounds__(256) void cast_in_t(const float* __restrict__ Xr,
                                                 const float* __restrict__ Xi,
                                                 bf16* __restrict__ Xr16, bf16* __restrict__ Xi16,
                                                 bf16* __restrict__ Xrt,  bf16* __restrict__ Xit) {
    int f0 = blockIdx.x * 64, n0 = blockIdx.y * 64;
    __shared__ bf16 sR[64][65];
    __shared__ bf16 sI[64][65];
    int t = threadIdx.x;
    #pragma unroll 4
    for (int e = 0; e < 16; ++e) {
        int idx = t + e * 256; int r = idx >> 6, c = idx & 63;
        size_t gi = (size_t)(n0 + r) * FDIM + f0 + c;
        float vr = Xr[gi], vi = Xi[gi];
        Xr16[gi] = (bf16)vr; Xi16[gi] = (bf16)vi;
        sR[c][r] = (bf16)vr; sI[c][r] = (bf16)vi;
    }
    __syncthreads();
    #pragma unroll 4
    for (int e = 0; e < 16; ++e) {
        int idx = t + e * 256; int r = idx >> 6, c = idx & 63;
        size_t go = (size_t)(f0 + r) * N_NODES + n0 + c;
        Xrt[go] = sR[r][c]; Xit[go] = sI[r][c];
    }
}

// bf16 [4096][256] -> [256][4096] transpose, two matrices. grid (4, 64).
__global__ __launch_bounds__(256) void transpose2_k(const bf16* __restrict__ inR,
                                                    const bf16* __restrict__ inI,
                                                    bf16* __restrict__ outR,
                                                    bf16* __restrict__ outI) {
    int f0 = blockIdx.x * 64, n0 = blockIdx.y * 64;
    __shared__ bf16 sR[64][65];
    __shared__ bf16 sI[64][65];
    int t = threadIdx.x;
    #pragma unroll 4
    for (int e = 0; e < 16; ++e) {
        int idx = t + e * 256; int r = idx >> 6, c = idx & 63;
        size_t gi = (size_t)(n0 + r) * FDIM + f0 + c;
        sR[c][r] = inR[gi]; sI[c][r] = inI[gi];
    }
    __syncthreads();
    #pragma unroll 4
    for (int e = 0; e < 16; ++e) {
        int idx = t + e * 256; int r = idx >> 6, c = idx & 63;
        size_t go = (size_t)(f0 + r) * N_NODES + n0 + c;
        outR[go] = sR[r][c]; outI[go] = sI[r][c];
    }
}

// cast W [3][256][256] -> Wt bf16 [256][768], Wt[n][o*256+k] = W[o][k][n]
__global__ __launch_bounds__(256) void cast_w(const float* __restrict__ W,
                                              bf16* __restrict__ Wt) {
    int idx = blockIdx.x * 256 + threadIdx.x;
    if (idx < 256 * 768) {
        int nout = idx / 768, kk = idx - nout * 768;
        int o = kk >> 8, k = kk & 255;
        Wt[idx] = (bf16)W[((size_t)o * 256 + k) * 256 + nout];
    }
}

// ---------------------------------------------------------------------------
// 5. Complex GEMM, split-K x2, double-buffered LDS, xor-swizzled tiles.
//    grid: 512 blocks 1D. b -> mt = b&63, nt = (b>>6)&3, kh = b>>8.
//    Writes fp32 partial sums: Pr/Pi + kh*NF (raw RR-II and OI sums).
// ---------------------------------------------------------------------------
__global__ __launch_bounds__(256, 2) void cspmm_mfma(
    const bf16* __restrict__ Lr, const bf16* __restrict__ Li,
    const bf16* __restrict__ Brt, const bf16* __restrict__ Bit,
    float* __restrict__ Pr, float* __restrict__ Pi)
{
    __shared__ __align__(16) bf16 sbuf[2][4][64 * 64];

    const int b  = blockIdx.x;
    const int mt = b & 63;
    const int nt = (b >> 6) & 3;
    const int kh = b >> 8;
    const int rowBase = mt * 64;
    const int colBase = nt * 64;

    const int tid  = threadIdx.x;
    const int wave = tid >> 6;
    const int lane = tid & 63;

    const bf16* gmat = (wave == 0) ? Lr : (wave == 1) ? Li : (wave == 2) ? Brt : Bit;
    const int gRow0  = (wave < 2) ? rowBase : colBase;
    const size_t kOff0 = (size_t)kh * 2048;
    const bf16* gbase = gmat + (size_t)gRow0 * N_NODES + kOff0;
    const int sr = lane >> 3;   // row-within-chunk
    const int sb = lane & 7;    // 16B block position in LDS row

    f32x4 accRR[2][2] = {}, accII[2][2] = {}, accOI[2][2] = {};
    const int wm = wave & 1, wn = wave >> 1;

    // stage one 64x64 bf16 tile (this wave's matrix) with xor swizzle
    auto stage = [&](int buf, int kb) {
        bf16* s = sbuf[buf][wave];
        const bf16* g0 = gbase + kb;
        #pragma unroll
        for (int ch = 0; ch < 8; ++ch) {
            int r  = ch * 8 + sr;
            int bg = sb ^ (r & 7);
            gld_lds16(g0 + (size_t)r * N_NODES + bg * 8, s + ch * 512);
        }
    };

    stage(0, 0);
    for (int it = 0; it < 32; ++it) {
        __syncthreads();                       // staged buf (it&1) ready; prior reads of other buf done
        if (it + 1 < 32) stage((it + 1) & 1, (it + 1) * 64);
        const bf16* sLr_ = sbuf[it & 1][0];
        const bf16* sLi_ = sbuf[it & 1][1];
        const bf16* sBr_ = sbuf[it & 1][2];
        const bf16* sBi_ = sbuf[it & 1][3];

        #pragma unroll
        for (int ks = 0; ks < 2; ++ks) {
            bf16x8 aR[2], aI[2], bR[2], bI[2];
            #pragma unroll
            for (int m = 0; m < 2; ++m) {
                int r  = wm * 32 + m * 16 + (lane & 15);
                int bl = (ks * 4 + (lane >> 4)) ^ (r & 7);
                aR[m] = *(const bf16x8*)&sLr_[r * 64 + bl * 8];
                aI[m] = *(const bf16x8*)&sLi_[r * 64 + bl * 8];
            }
            #pragma unroll
            for (int n = 0; n < 2; ++n) {
                int c  = wn * 32 + n * 16 + (lane & 15);
                int bl = (ks * 4 + (lane >> 4)) ^ (c & 7);
                bR[n] = *(const bf16x8*)&sBr_[c * 64 + bl * 8];
                bI[n] = *(const bf16x8*)&sBi_[c * 64 + bl * 8];
            }
            #pragma unroll
            for (int m = 0; m < 2; ++m)
                #pragma unroll
                for (int n = 0; n < 2; ++n) {
                    accRR[m][n] = __builtin_amdgcn_mfma_f32_16x16x32_bf16(aR[m], bR[n], accRR[m][n], 0, 0, 0);
                    accII[m][n] = __builtin_amdgcn_mfma_f32_16x16x32_bf16(aI[m], bI[n], accII[m][n], 0, 0, 0);
                    accOI[m][n] = __builtin_amdgcn_mfma_f32_16x16x32_bf16(aR[m], bI[n], accOI[m][n], 0, 0, 0);
                    accOI[m][n] = __builtin_amdgcn_mfma_f32_16x16x32_bf16(aI[m], bR[n], accOI[m][n], 0, 0, 0);
                }
        }
    }

    float* pr = Pr + (size_t)kh * NF;
    float* pi = Pi + (size_t)kh * NF;
    #pragma unroll
    for (int m = 0; m < 2; ++m)
        #pragma unroll
        for (int n = 0; n < 2; ++n) {
            int row0 = rowBase + wm * 32 + m * 16 + (lane >> 4) * 4;
            int col  = colBase + wn * 32 + n * 16 + (lane & 15);
            #pragma unroll
            for (int r = 0; r < 4; ++r) {
                size_t idx = (size_t)(row0 + r) * FDIM + col;
                pr[idx] = accRR[m][n][r] - accII[m][n][r];
                pi[idx] = accOI[m][n][r];
            }
        }
}

// ---------------------------------------------------------------------------
// 6. Split-K reduce + epilogue: v = alpha*(P0+P1) [+ beta*C0]; writes bf16
//    row-major and optionally bf16 transposed (LDS-tiled). grid (4, 64).
// ---------------------------------------------------------------------------
__global__ __launch_bounds__(256) void reduce_k(
    const float* __restrict__ Pr, const float* __restrict__ Pi,
    const float* __restrict__ C0r, const float* __restrict__ C0i,
    float alpha, float beta,
    bf16* __restrict__ OutR, bf16* __restrict__ OutI,
    bf16* __restrict__ OutTr, bf16* __restrict__ OutTi)
{
    int f0 = blockIdx.x * 64, n0 = blockIdx.y * 64;
    __shared__ bf16 sR[64][65];
    __shared__ bf16 sI[64][65];
    int t = threadIdx.x;
    #pragma unroll 4
    for (int e = 0; e < 16; ++e) {
        int idx = t + e * 256; int r = idx >> 6, c = idx & 63;
        size_t gi = (size_t)(n0 + r) * FDIM + f0 + c;
        float vr = alpha * (Pr[gi] + Pr[NF + gi]);
        float vi = alpha * (Pi[gi] + Pi[NF + gi]);
        if (C0r) { vr += beta * C0r[gi]; vi += beta * C0i[gi]; }
        OutR[gi] = (bf16)vr; OutI[gi] = (bf16)vi;
        sR[c][r] = (bf16)vr; sI[c][r] = (bf16)vi;
    }
    if (OutTr) {
        __syncthreads();
        #pragma unroll 4
        for (int e = 0; e < 16; ++e) {
            int idx = t + e * 256; int r = idx >> 6, c = idx & 63;
            size_t go = (size_t)(f0 + r) * N_NODES + n0 + c;
            OutTr[go] = sR[r][c]; OutTi[go] = sI[r][c];
        }
    }
}

// ---------------------------------------------------------------------------
// 7. wapply via MFMA: S = [Z0|Z1|Z2] @ Wcat (K=768); Or = b - Si; Oi = b + Sr
// ---------------------------------------------------------------------------
__global__ __launch_bounds__(256) void wapply_mfma(
    const bf16* __restrict__ Z0r, const bf16* __restrict__ Z0i,
    const bf16* __restrict__ Z1r, const bf16* __restrict__ Z1i,
    const bf16* __restrict__ Z2r, const bf16* __restrict__ Z2i,
    const bf16* __restrict__ Wt,      // [256][768]
    const float* __restrict__ bias,   // [256]
    float* __restrict__ O32r, float* __restrict__ O32i,
    bf16* __restrict__ O16r_r, bf16* __restrict__ O16r_i)
{
    __shared__ __align__(16) bf16 sZr[64 * 32];
    __shared__ __align__(16) bf16 sZi[64 * 32];
    __shared__ __align__(16) bf16 sW [64 * 32];

    const int tid  = threadIdx.x;
    const int wave = tid >> 6;
    const int lane = tid & 63;
    const int rowBase = blockIdx.y * 64;
    const int colBase = blockIdx.x * 64;

    const int srow = lane >> 2;
    const int skc  = (lane & 3) * 8;

    f32x4 accSr[2][2] = {}, accSi[2][2] = {};
    const int wm = wave & 1, wn = wave >> 1;
    const int fr = lane & 15;
    const int fk = (lane >> 4) * 8;

    for (int kb = 0; kb < 3 * FDIM; kb += 32) {
        int order = kb >> 8;
        int kloc  = kb & 255;
        if (wave == 0 || wave == 1) {
            const bf16* z;
            if (wave == 0) z = (order == 0) ? Z0r : (order == 1) ? Z1r : Z2r;
            else           z = (order == 0) ? Z0i : (order == 1) ? Z1i : Z2i;
            bf16* s = (wave == 0) ? sZr : sZi;
            const bf16* g = z + (size_t)(rowBase + srow) * FDIM + kloc + skc;
            #pragma unroll
            for (int t = 0; t < 4; ++t)
                gld_lds16(g + (size_t)t * 16 * FDIM, s + t * 512);
        } else if (wave == 2) {
            const bf16* g = Wt + (size_t)(colBase + srow) * 768 + kb + skc;
            #pragma unroll
            for (int t = 0; t < 4; ++t)
                gld_lds16(g + (size_t)t * 16 * 768, sW + t * 512);
        }
        __syncthreads();

        bf16x8 zr[2], zi[2], wv[2];
        #pragma unroll
        for (int m = 0; m < 2; ++m) {
            int r = wm * 32 + m * 16 + fr;
            zr[m] = *(const bf16x8*)&sZr[r * 32 + fk];
            zi[m] = *(const bf16x8*)&sZi[r * 32 + fk];
        }
        #pragma unroll
        for (int n = 0; n < 2; ++n) {
            int c = wn * 32 + n * 16 + fr;
            wv[n] = *(const bf16x8*)&sW[c * 32 + fk];
        }
        #pragma unroll
        for (int m = 0; m < 2; ++m)
            #pragma unroll
            for (int n = 0; n < 2; ++n) {
                accSr[m][n] = __builtin_amdgcn_mfma_f32_16x16x32_bf16(zr[m], wv[n], accSr[m][n], 0, 0, 0);
                accSi[m][n] = __builtin_amdgcn_mfma_f32_16x16x32_bf16(zi[m], wv[n], accSi[m][n], 0, 0, 0);
            }
        __syncthreads();
    }

    #pragma unroll
    for (int m = 0; m < 2; ++m)
        #pragma unroll
        for (int n = 0; n < 2; ++n) {
            int row0 = rowBase + wm * 32 + m * 16 + (lane >> 4) * 4;
            int col  = colBase + wn * 32 + n * 16 + (lane & 15);
            float bv = bias[col];
            #pragma unroll
            for (int r = 0; r < 4; ++r) {
                float vr = bv - accSi[m][n][r];
                float vi = bv + accSr[m][n][r];
                size_t idx = (size_t)(row0 + r) * FDIM + col;
                if (O32r)   { O32r[idx] = vr; O32i[idx] = vi; }
                if (O16r_r) { O16r_r[idx] = (bf16)vr; O16r_i[idx] = (bf16)vi; }
            }
        }
}

// ---------------------------------------------------------------------------
// 8. Head: logits = [r,i] @ Wc^T + bc; out = log_softmax
// ---------------------------------------------------------------------------
__global__ __launch_bounds__(64) void head_k(
    const float* __restrict__ Yr, const float* __restrict__ Yi,
    const float* __restrict__ Wc,   // [40][512]
    const float* __restrict__ bc,   // [40]
    float* __restrict__ out)        // [N][40]
{
    int n = blockIdx.x;
    int t = threadIdx.x;
    __shared__ float x[2 * FDIM];
    for (int k = t; k < FDIM; k += 64) {
        x[k]        = Yr[(size_t)n * FDIM + k];
        x[FDIM + k] = Yi[(size_t)n * FDIM + k];
    }
    __syncthreads();

    float logit = -INFINITY;
    if (t < CDIM) {
        float s = bc[t];
        const float* w = Wc + (size_t)t * (2 * FDIM);
        #pragma unroll 8
        for (int k = 0; k < 2 * FDIM; ++k) s += x[k] * w[k];
        logit = s;
    }
    float m = logit;
    for (int off = 32; off; off >>= 1) m = fmaxf(m, __shfl_down(m, off));
    m = __shfl(m, 0);
    float e = (t < CDIM) ? expf(logit - m) : 0.f;
    float se = e;
    for (int off = 32; off; off >>= 1) se += __shfl_down(se, off);
    se = __shfl(se, 0);
    float lse = m + logf(se);
    if (t < CDIM) out[(size_t)n * CDIM + t] = logit - lse;
}

// ---------------------------------------------------------------------------
// Launcher
// ---------------------------------------------------------------------------
extern "C" void kernel_launch(void* const* d_in, const int* in_sizes, int n_in,
                              void* d_out, int out_size, void* d_ws, size_t ws_size,
                              hipStream_t stream) {
    const float* real = (const float*)d_in[0];
    const float* imag = (const float*)d_in[1];
    const int*   edges = (const int*)d_in[2];
    const float* q    = (const float*)d_in[3];
    const float* ew   = (const float*)d_in[4];
    const float* W1   = (const float*)d_in[5];
    const float* b1   = (const float*)d_in[6];
    const float* W2   = (const float*)d_in[7];
    const float* b2   = (const float*)d_in[8];
    const float* Wc   = (const float*)d_in[9];
    const float* bc   = (const float*)d_in[10];
    float* out = (float*)d_out;

    // ---- workspace carve-up ----
    char* w = (char*)d_ws;
    float* A      = (float*)w;  w += NN * 4;                 // 64 MB (dead after build_L)
    float* colsum = (float*)w;  w += N_NODES * 4;
    float* rowsum = (float*)w;  w += N_NODES * 4;
    float* dinv   = (float*)w;  w += N_NODES * 4;
    w += 4096;
    bf16* Lr16 = (bf16*)w;  w += NN * 2;                     // 32 MB
    bf16* Li16 = (bf16*)w;  w += NN * 2;                     // 32 MB
    bf16* Xr16  = (bf16*)w; w += NF * 2;
    bf16* Xi16  = (bf16*)w; w += NF * 2;
    bf16* Xr16t = (bf16*)w; w += NF * 2;
    bf16* Xi16t = (bf16*)w; w += NF * 2;
    bf16* Z1r16  = (bf16*)w; w += NF * 2;
    bf16* Z1i16  = (bf16*)w; w += NF * 2;
    bf16* Z1r16t = (bf16*)w; w += NF * 2;
    bf16* Z1i16t = (bf16*)w; w += NF * 2;
    bf16* Z2r16  = (bf16*)w; w += NF * 2;
    bf16* Z2i16  = (bf16*)w; w += NF * 2;
    float* Y1r = (float*)w; w += NF * 4;
    float* Y1i = (float*)w; w += NF * 4;
    bf16* Y1r16  = (bf16*)w; w += NF * 2;
    bf16* Y1i16  = (bf16*)w; w += NF * 2;
    bf16* Y1r16t = (bf16*)w; w += NF * 2;
    bf16* Y1i16t = (bf16*)w; w += NF * 2;
    bf16* W1t = (bf16*)w; w += 256 * 768 * 2;
    bf16* W2t = (bf16*)w; w += 256 * 768 * 2;
    // Aliases into dead-A region: split-K partials (16 MB) + Y2 (8 MB)
    float* Pr  = A;                  // 2*NF fp32 = 8 MB
    float* Pi  = A + 2 * NF;         // 8 MB
    float* Y2r = A + 4 * NF;         // 4 MB
    float* Y2i = A + 5 * NF;         // 4 MB

    // zero A + colsum + rowsum (accumulated into)
    hipMemsetAsync(A, 0, NN * 4 + 2 * N_NODES * 4, stream);

    scatter_edges<<<(NEDGE + 255) / 256, 256, 0, stream>>>(edges, ew, A);
    degree_k<<<dim3(4, 64), 256, 0, stream>>>(A, rowsum, colsum);
    dinv_k<<<16, 256, 0, stream>>>(rowsum, colsum, dinv);
    build_L_pair<<<dim3(64, 64), 256, 0, stream>>>(A, Lr16, Li16, dinv, q);

    cast_in_t<<<dim3(4, 64), 256, 0, stream>>>(real, imag, Xr16, Xi16, Xr16t, Xi16t);
    cast_w<<<768, 256, 0, stream>>>(W1, W1t);
    cast_w<<<768, 256, 0, stream>>>(W2, W2t);

    dim3 gW(FDIM / 64, N_NODES / 64);   // (4, 64)
    dim3 gR(4, 64);

    // ---- Layer 1 ----
    cspmm_mfma<<<512, 256, 0, stream>>>(Lr16, Li16, Xr16t, Xi16t, Pr, Pi);
    reduce_k<<<gR, 256, 0, stream>>>(Pr, Pi, nullptr, nullptr, 1.f, 0.f,
                                     Z1r16, Z1i16, Z1r16t, Z1i16t);
    cspmm_mfma<<<512, 256, 0, stream>>>(Lr16, Li16, Z1r16t, Z1i16t, Pr, Pi);
    reduce_k<<<gR, 256, 0, stream>>>(Pr, Pi, real, imag, 2.f, -1.f,
                                     Z2r16, Z2i16, nullptr, nullptr);
    wapply_mfma<<<gW, 256, 0, stream>>>(Xr16, Xi16, Z1r16, Z1i16, Z2r16, Z2i16,
                                        W1t, b1, Y1r, Y1i, Y1r16, Y1i16);
    transpose2_k<<<gR, 256, 0, stream>>>(Y1r16, Y1i16, Y1r16t, Y1i16t);

    // ---- Layer 2 ----
    cspmm_mfma<<<512, 256, 0, stream>>>(Lr16, Li16, Y1r16t, Y1i16t, Pr, Pi);
    reduce_k<<<gR, 256, 0, stream>>>(Pr, Pi, nullptr, nullptr, 1.f, 0.f,
                                     Z1r16, Z1i16, Z1r16t, Z1i16t);
    cspmm_mfma<<<512, 256, 0, stream>>>(Lr16, Li16, Z1r16t, Z1i16t, Pr, Pi);
    reduce_k<<<gR, 256, 0, stream>>>(Pr, Pi, Y1r, Y1i, 2.f, -1.f,
                                     Z2r16, Z2i16, nullptr, nullptr);
    wapply_mfma<<<gW, 256, 0, stream>>>(Y1r16, Y1i16, Z1r16, Z1i16, Z2r16, Z2i16,
                                        W2t, b2, Y2r, Y2i, nullptr, nullptr);

    // ---- Head ----
    head_k<<<N_NODES, 64, 0, stream>>>(Y2r, Y2i, Wc, bc, out);
}